// Round 1
// baseline (79.706 us; speedup 1.0000x reference)
//
#include <hip/hip_runtime.h>
#include <hip/hip_bf16.h>
#include <math.h>

#define B_ROWS 4096
#define NTOT   8192
#define DDIM   256
#define INV_T  2.0f           // 1 / temperature(0.5)
#define EXP2_SCALE 2.8853900817779268f  // INV_T * log2(e)

typedef __attribute__((ext_vector_type(8))) short  short8;   // 8 bf16
typedef __attribute__((ext_vector_type(4))) float  f32x4;

static __device__ inline unsigned short f2bf(float x) {
    union { float f; unsigned u; } v; v.f = x;
    unsigned r = v.u + 0x7fffu + ((v.u >> 16) & 1u);  // RNE
    return (unsigned short)(r >> 16);
}
static __device__ inline float bf2f(unsigned short h) {
    union { unsigned u; float f; } v; v.u = ((unsigned)h) << 16;
    return v.f;
}

// ---- kernel 1: row-normalize concat(z_i, z_j) -> bf16 zn[8192][256] ----
__global__ __launch_bounds__(256) void norm_kernel(
        const float* __restrict__ zi, const float* __restrict__ zj,
        unsigned short* __restrict__ zn) {
    int row  = blockIdx.x * 4 + (threadIdx.x >> 6);
    int lane = threadIdx.x & 63;
    const float* src = (row < B_ROWS) ? zi + (size_t)row * DDIM
                                      : zj + (size_t)(row - B_ROWS) * DDIM;
    float4 v = reinterpret_cast<const float4*>(src)[lane];  // 4 floats/lane
    float ss = v.x*v.x + v.y*v.y + v.z*v.z + v.w*v.w;
    #pragma unroll
    for (int o = 32; o > 0; o >>= 1) ss += __shfl_xor(ss, o);
    float inv = 1.0f / fmaxf(sqrtf(ss), 1e-8f);
    ushort4 h;
    h.x = f2bf(v.x * inv); h.y = f2bf(v.y * inv);
    h.z = f2bf(v.z * inv); h.w = f2bf(v.w * inv);
    *reinterpret_cast<ushort4*>(zn + (size_t)row * DDIM + lane * 4) = h;
}

// ---- kernel 2: positive-pair similarities simpos[i] = dot(zn[i], zn[i+B]) * INV_T ----
__global__ __launch_bounds__(256) void simpos_kernel(
        const unsigned short* __restrict__ zn, float* __restrict__ simpos) {
    int i    = blockIdx.x * 4 + (threadIdx.x >> 6);
    int lane = threadIdx.x & 63;
    ushort4 a = *reinterpret_cast<const ushort4*>(zn + (size_t)i * DDIM + lane * 4);
    ushort4 b = *reinterpret_cast<const ushort4*>(zn + (size_t)(i + B_ROWS) * DDIM + lane * 4);
    float s = bf2f(a.x)*bf2f(b.x) + bf2f(a.y)*bf2f(b.y)
            + bf2f(a.z)*bf2f(b.z) + bf2f(a.w)*bf2f(b.w);
    #pragma unroll
    for (int o = 32; o > 0; o >>= 1) s += __shfl_xor(s, o);
    if (lane == 0) simpos[i] = s * INV_T;
}

// ---- kernel 3: fused sim + exp + row-sum ----
// grid (64, 8): blockIdx.x = 128-row tile, blockIdx.y = 1024-col split.
// 4 waves/block, each wave owns 32 rows (2 rowsets of 16). 64-col LDS tiles.
__global__ __launch_bounds__(256) void sim_kernel(
        const unsigned short* __restrict__ zn, float* __restrict__ sumexp) {
    constexpr int COLS_PER_BLOCK = 1024;
    constexpr int TILE_COLS = 64;
    constexpr int ROW_BYTES = DDIM * 2;  // 512 B per row
    __shared__ __align__(16) unsigned char tile[TILE_COLS * ROW_BYTES];  // 32 KB

    int wid  = threadIdx.x >> 6;
    int lane = threadIdx.x & 63;
    int l15  = lane & 15;
    int l4   = lane >> 4;
    int rowBase      = blockIdx.x * 128 + wid * 32;
    int colSplitBase = blockIdx.y * COLS_PER_BLOCK;

    // A fragments: rows held in registers the whole kernel (16B each, 16 total)
    short8 a[2][8];
    #pragma unroll
    for (int rs = 0; rs < 2; ++rs) {
        const unsigned short* ap = zn + (size_t)(rowBase + rs * 16 + l15) * DDIM;
        #pragma unroll
        for (int c = 0; c < 8; ++c)
            a[rs][c] = *reinterpret_cast<const short8*>(ap + c * 32 + l4 * 8);
    }

    float sums[2][4] = {{0.f,0.f,0.f,0.f},{0.f,0.f,0.f,0.f}};

    for (int it = 0; it < COLS_PER_BLOCK / TILE_COLS; ++it) {
        int colBase = colSplitBase + it * TILE_COLS;
        __syncthreads();  // protect LDS before overwrite
        // stage 64 cols x 256 k (bf16) = 32 KB; 2048 x 16B chunks / 256 thr = 8 each
        #pragma unroll
        for (int p = 0; p < 8; ++p) {
            int id = p * 256 + threadIdx.x;
            int tr = id >> 5;          // tile row (col index)
            int ck = id & 31;          // 16B chunk within row
            uint4 v = *reinterpret_cast<const uint4*>(
                zn + (size_t)(colBase + tr) * DDIM + ck * 8);
            int off = tr * ROW_BYTES + ((ck * 16) ^ ((tr & 7) << 4));  // XOR swizzle
            *reinterpret_cast<uint4*>(tile + off) = v;
        }
        __syncthreads();

        #pragma unroll
        for (int sub = 0; sub < 4; ++sub) {
            // B fragments for this 16-col subtile (shared across both rowsets)
            short8 b[8];
            int trr = sub * 16 + l15;
            int rowoff = trr * ROW_BYTES;
            int swz = (trr & 7) << 4;
            #pragma unroll
            for (int c = 0; c < 8; ++c) {
                int o = c * 64 + l4 * 16;
                b[c] = *reinterpret_cast<const short8*>(tile + rowoff + (o ^ swz));
            }
            int gcol = colBase + sub * 16 + l15;
            #pragma unroll
            for (int rs = 0; rs < 2; ++rs) {
                f32x4 acc = {0.f, 0.f, 0.f, 0.f};
                #pragma unroll
                for (int c = 0; c < 8; ++c)
                    acc = __builtin_amdgcn_mfma_f32_16x16x32_bf16(a[rs][c], b[c], acc, 0, 0, 0);
                int growb = rowBase + rs * 16 + l4 * 4;
                #pragma unroll
                for (int j = 0; j < 4; ++j) {
                    float e = exp2f(acc[j] * EXP2_SCALE);
                    e = (growb + j == gcol) ? 0.f : e;   // mask diagonal
                    sums[rs][j] += e;
                }
            }
        }
    }

    // reduce over the 16-lane column group (xor masks stay within group)
    #pragma unroll
    for (int rs = 0; rs < 2; ++rs)
        #pragma unroll
        for (int j = 0; j < 4; ++j) {
            float s = sums[rs][j];
            #pragma unroll
            for (int m = 8; m >= 1; m >>= 1) s += __shfl_xor(s, m);
            sums[rs][j] = s;
        }
    if (l15 == 0) {
        #pragma unroll
        for (int rs = 0; rs < 2; ++rs)
            #pragma unroll
            for (int j = 0; j < 4; ++j)
                atomicAdd(&sumexp[rowBase + rs * 16 + l4 * 4 + j], sums[rs][j]);
    }
}

// ---- kernel 4: loss = sum_r (log(sumexp[r]) - simpos[r % B]) / N ----
__global__ __launch_bounds__(256) void finalize_kernel(
        const float* __restrict__ sumexp, const float* __restrict__ simpos,
        float* __restrict__ out) {
    __shared__ float red[4];
    float acc = 0.f;
    for (int r = threadIdx.x; r < NTOT; r += 256)
        acc += logf(sumexp[r]) - simpos[r & (B_ROWS - 1)];
    #pragma unroll
    for (int o = 32; o > 0; o >>= 1) acc += __shfl_xor(acc, o);
    if ((threadIdx.x & 63) == 0) red[threadIdx.x >> 6] = acc;
    __syncthreads();
    if (threadIdx.x == 0)
        out[0] = (red[0] + red[1] + red[2] + red[3]) / (float)NTOT;
}

extern "C" void kernel_launch(void* const* d_in, const int* in_sizes, int n_in,
                              void* d_out, int out_size, void* d_ws, size_t ws_size,
                              hipStream_t stream) {
    const float* zi = (const float*)d_in[0];
    const float* zj = (const float*)d_in[1];
    float* out = (float*)d_out;

    unsigned short* zn = (unsigned short*)d_ws;                       // 4 MB
    float* sumexp = (float*)((char*)d_ws + (size_t)NTOT * DDIM * 2);  // 32 KB
    float* simpos = sumexp + NTOT;                                    // 16 KB

    hipMemsetAsync(sumexp, 0, NTOT * sizeof(float), stream);
    norm_kernel<<<NTOT / 4, 256, 0, stream>>>(zi, zj, zn);
    simpos_kernel<<<B_ROWS / 4, 256, 0, stream>>>(zn, simpos);
    dim3 grid(64, 8);
    sim_kernel<<<grid, 256, 0, stream>>>(zn, sumexp);
    finalize_kernel<<<1, 256, 0, stream>>>(sumexp, simpos, out);
}